// Round 9
// baseline (891.764 us; speedup 1.0000x reference)
//
#include <hip/hip_runtime.h>
#include <hip/hip_bf16.h>

typedef __attribute__((ext_vector_type(8))) short bf16x8;
typedef __attribute__((ext_vector_type(4))) short bf16x4;
typedef __attribute__((ext_vector_type(4))) float f32x4;
typedef __attribute__((ext_vector_type(8))) unsigned short ushort8;

__device__ __forceinline__ float bf2f(unsigned short u) {
  union { unsigned int i; float f; } v; v.i = ((unsigned int)u) << 16; return v.f;
}
__device__ __forceinline__ unsigned short f2bf(float f) {
  __hip_bfloat16 h = __float2bfloat16(f);
  unsigned short u; __builtin_memcpy(&u, &h, 2); return u;
}
__device__ __forceinline__ unsigned int pk2(float a, float b) {
  return (unsigned int)f2bf(a) | ((unsigned int)f2bf(b) << 16);
}

// K=16 bf16 MFMA: A/B frag = 4 bf16 (lane: row/col = l&15, k = (l>>4)*4 + j)
__device__ __forceinline__ f32x4 mfma16(bf16x4 a, bf16x4 b, f32x4 c) {
#if __has_builtin(__builtin_amdgcn_mfma_f32_16x16x16bf16_1k)
  return __builtin_amdgcn_mfma_f32_16x16x16bf16_1k(a, b, c, 0, 0, 0);
#else
  asm volatile("v_mfma_f32_16x16x16_bf16 %0, %1, %2, %0\n\ts_nop 7\n\ts_nop 7"
               : "+v"(c) : "v"(a), "v"(b));
  return c;
#endif
}

// ---------------------------------------------------------------------------
// Kernel P: convert qkv_w (384x128) and proj_w (128x128) fp32 -> bf16 in ws
// ---------------------------------------------------------------------------
__global__ void k_prep(const float* __restrict__ qkvw, const float* __restrict__ projw,
                       unsigned short* __restrict__ qkvw_bf,
                       unsigned short* __restrict__ projw_bf) {
  int t = blockIdx.x * 256 + threadIdx.x;
  int i = t * 4;
  const float* src;
  unsigned short* dst;
  int idx;
  if (i < 49152) { src = qkvw; dst = qkvw_bf; idx = i; }
  else           { src = projw; dst = projw_bf; idx = i - 49152; }
  float4 v = *(const float4*)(src + idx);
  union { unsigned short u[4]; uint2 v2; } o;
  o.u[0] = f2bf(v.x); o.u[1] = f2bf(v.y); o.u[2] = f2bf(v.z); o.u[3] = f2bf(v.w);
  *(uint2*)(dst + idx) = o.v2;
}

// ---------------------------------------------------------------------------
// Kernel B: padded bias table  biasp[h][64][64]; -1e30 outside 49x49
// ---------------------------------------------------------------------------
__global__ void k_bias(const float* __restrict__ bt,
                       const int* __restrict__ ri,
                       float* __restrict__ bp) {
  int t = blockIdx.x * 256 + threadIdx.x;   // 16384
  int hq = t >> 12;
  int q  = (t >> 6) & 63;
  int k  = t & 63;
  float v = -1e30f;
  if (q < 49 && k < 49) v = bt[ri[q * 49 + k] * 4 + hq];
  bp[t] = v;
}

// ---------------------------------------------------------------------------
// Kernel M: padded mask table  maskp[wrem][64][64]; -1e30 outside 49x49
// ---------------------------------------------------------------------------
__global__ void k_mask(const float* __restrict__ am, float* __restrict__ mp) {
  int t = blockIdx.x * 256 + threadIdx.x;   // 1048576
  int w = t >> 12;
  int q = (t >> 6) & 63;
  int k = t & 63;
  float v = -1e30f;
  if (q < 49 && k < 49) v = am[w * 2401 + q * 49 + k];
  mp[t] = v;
}

// ---------------------------------------------------------------------------
// Kernel 1: LayerNorm over C + cyclic shift (-3,-3) + window partition
// two-pass (second pass hits L2/L3); no big register array -> no spills
// ---------------------------------------------------------------------------
__global__ __launch_bounds__(256, 4) void k_ln(const float* __restrict__ x,
                                               const float* __restrict__ nw,
                                               const float* __restrict__ nb,
                                               unsigned short* __restrict__ xw) {
  int p = blockIdx.x * 256 + threadIdx.x;   // 0 .. 401407 (exact)
  int b = p / 12544;
  int r = p - b * 12544;
  int hh = r / 112;
  int wp = r - hh * 112;
  const float* bx = x + (size_t)b * 1605632 + r;  // b*C*H*W + h*W + w

  float sum = 0.f, ss = 0.f;
  #pragma unroll 16
  for (int c = 0; c < 128; ++c) {
    float v = bx[(size_t)c * 12544];
    sum += v; ss += v * v;
  }
  float mu = sum * 0.0078125f;
  float var = ss * 0.0078125f - mu * mu;
  float rstd = rsqrtf(var + 1e-5f);

  // destination (shifted coords): h' = (hh-3) mod 112
  int h2 = hh + 109; if (h2 >= 112) h2 -= 112;
  int w2 = wp + 109; if (w2 >= 112) w2 -= 112;
  int wh = h2 / 7, ii = h2 - wh * 7;
  int ww = w2 / 7, jj = w2 - ww * 7;
  int winl = (b * 16 + wh) * 16 + ww;
  unsigned short* dst = xw + ((size_t)winl * 49 + ii * 7 + jj) * 128;

  #pragma unroll
  for (int g = 0; g < 4; ++g) {
    unsigned int pk[16];
    #pragma unroll
    for (int q = 0; q < 16; ++q) {
      int c = g * 32 + 2 * q;
      float v0 = bx[(size_t)c * 12544];
      float v1 = bx[(size_t)(c + 1) * 12544];
      float y0 = (v0 - mu) * rstd * nw[c]     + nb[c];
      float y1 = (v1 - mu) * rstd * nw[c + 1] + nb[c + 1];
      pk[q] = (unsigned int)f2bf(y0) | ((unsigned int)f2bf(y1) << 16);
    }
    uint4* d4 = (uint4*)(dst + g * 32);
    #pragma unroll
    for (int k = 0; k < 4; ++k)
      d4[k] = make_uint4(pk[4 * k], pk[4 * k + 1], pk[4 * k + 2], pk[4 * k + 3]);
  }
}

// ---------------------------------------------------------------------------
// Kernel 2: fused window attention. 1 block = 1 window, wave h = head h.
// Q, K, P live entirely in REGISTERS (K=16 MFMAs consume the C-layout of the
// producing MFMAs directly). LDS only: X staging [0,16K) + per-head V^T/O
// [16K + h*4K, +4K). 32 KiB total, 2 barriers.
// ---------------------------------------------------------------------------
__global__ __launch_bounds__(256, 4) void k_attn(
    const unsigned short* __restrict__ xw,
    const unsigned short* __restrict__ qkvw,
    const float* __restrict__ qkvb,
    const unsigned short* __restrict__ projw,
    const float* __restrict__ projb,
    const float* __restrict__ biasp,
    const float* __restrict__ maskp,
    unsigned short* __restrict__ yw) {
  __shared__ __attribute__((aligned(16))) char smem[32768];
  const int tid  = threadIdx.x;
  const int lane = tid & 63;
  const int h    = tid >> 6;
  const int m15  = lane & 15;
  const int quad = lane >> 4;
  const int win  = blockIdx.x;
  const int b    = win >> 8;
  const int wrem = win & 255;
  const int wh   = wrem >> 4;
  const int ww   = wrem & 15;
  const f32x4 fz = {0.f, 0.f, 0.f, 0.f};

  // ---- stage X window (49x128 bf16 -> 64 rows x 256B swizzled, zero pad) ----
  {
    const uint4* gsrc = (const uint4*)(xw + (size_t)win * 6272);
    #pragma unroll
    for (int it = 0; it < 4; ++it) {
      int cc = tid + it * 256;                 // 16B chunk index, 0..1023
      int row = cc >> 4, col = cc & 15;
      uint4 v = make_uint4(0u, 0u, 0u, 0u);
      if (cc < 784) v = gsrc[cc];
      *(uint4*)(smem + row * 256 + ((col ^ (row & 7)) << 4)) = v;
    }
  }
  __syncthreads();

  char* const vpb = smem + 16384 + h * 4096;   // V^T [32][128B], later O [64][64B]

  // ---- QKV, processed in two token-halves to bound VGPR pressure ----
  bf16x4 qq[2][4], kk[2][4];    // [sp(16-dim half)][mt]: frag k = quad*4+rr
  #pragma unroll
  for (int mh = 0; mh < 2; ++mh) {
    bf16x8 xf[2][4];
    #pragma unroll
    for (int m2 = 0; m2 < 2; ++m2) {
      int row = (mh * 2 + m2) * 16 + m15;
      #pragma unroll
      for (int kt = 0; kt < 4; ++kt)
        xf[m2][kt] = *(const bf16x8*)(smem + row * 256 + (((kt * 4 + quad) ^ (row & 7)) << 4));
    }
    // Q, K: swapped mfma(W, X) -> lane holds token=m15, dims quad*4+rr
    #pragma unroll
    for (int g = 0; g < 2; ++g) {
      #pragma unroll
      for (int sp = 0; sp < 2; ++sp) {
        int nt = g * 8 + 2 * h + sp;
        bf16x8 wfr[4];
        #pragma unroll
        for (int kt = 0; kt < 4; ++kt)
          wfr[kt] = *(const bf16x8*)(qkvw + (nt * 16 + m15) * 128 + kt * 32 + quad * 8);
        float4 b4 = *(const float4*)(qkvb + nt * 16 + quad * 4);
        #pragma unroll
        for (int m2 = 0; m2 < 2; ++m2) {
          int mt = mh * 2 + m2;
          f32x4 acc = fz;
          #pragma unroll
          for (int kt = 0; kt < 4; ++kt)
            acc = __builtin_amdgcn_mfma_f32_16x16x32_bf16(wfr[kt], xf[m2][kt], acc, 0, 0, 0);
          union { unsigned int u[2]; bf16x4 v; } pk;
          pk.u[0] = pk2(acc[0] + b4.x, acc[1] + b4.y);
          pk.u[1] = pk2(acc[2] + b4.z, acc[3] + b4.w);
          if (g) kk[sp][mt] = pk.v; else qq[sp][mt] = pk.v;
        }
      }
    }
    // V: normal mfma(X, W) -> lane holds dim=m15, tokens quad*4+rr -> LDS
    #pragma unroll
    for (int sp = 0; sp < 2; ++sp) {
      int nt = 16 + 2 * h + sp;
      bf16x8 wfr[4];
      #pragma unroll
      for (int kt = 0; kt < 4; ++kt)
        wfr[kt] = *(const bf16x8*)(qkvw + (nt * 16 + m15) * 128 + kt * 32 + quad * 8);
      float bias = qkvb[nt * 16 + m15];
      int dsub = sp * 16 + m15;
      #pragma unroll
      for (int m2 = 0; m2 < 2; ++m2) {
        int mt = mh * 2 + m2;
        f32x4 acc = fz;
        #pragma unroll
        for (int kt = 0; kt < 4; ++kt)
          acc = __builtin_amdgcn_mfma_f32_16x16x32_bf16(xf[m2][kt], wfr[kt], acc, 0, 0, 0);
        uint2 o;
        o.x = pk2(acc[0] + bias, acc[1] + bias);
        o.y = pk2(acc[2] + bias, acc[3] + bias);
        int chunk = mt * 2 + (quad >> 1);
        *(uint2*)(vpb + dsub * 128 + ((chunk ^ (dsub & 7)) << 4) + (quad & 1) * 8) = o;
      }
    }
  }

  // ---- S^T = K Q^T via K=16 MFMAs (operands straight from registers),
  //      softmax, P packed to registers ----
  bf16x4 pp[4][4];              // [mt(q-tile)][nt(k-tile)]: frag k = quad*4+rr
  const float* bp_ = biasp + h * 4096;
  const float* mp_ = maskp + wrem * 4096;
  #pragma unroll
  for (int mt = 0; mt < 4; ++mt) {
    int q = mt * 16 + m15;
    float sv[16];
    #pragma unroll
    for (int nt = 0; nt < 4; ++nt) {
      f32x4 s = mfma16(kk[0][nt], qq[0][mt], fz);
      s = mfma16(kk[1][nt], qq[1][mt], s);
      float4 bb = *(const float4*)(bp_ + q * 64 + nt * 16 + quad * 4);
      float4 mm = *(const float4*)(mp_ + q * 64 + nt * 16 + quad * 4);
      sv[nt * 4 + 0] = s[0] * 0.17677669529663687f + bb.x + mm.x;
      sv[nt * 4 + 1] = s[1] * 0.17677669529663687f + bb.y + mm.y;
      sv[nt * 4 + 2] = s[2] * 0.17677669529663687f + bb.z + mm.z;
      sv[nt * 4 + 3] = s[3] * 0.17677669529663687f + bb.w + mm.w;
    }
    float mx = sv[0];
    #pragma unroll
    for (int j = 1; j < 16; ++j) mx = fmaxf(mx, sv[j]);
    mx = fmaxf(mx, __shfl_xor(mx, 16));
    mx = fmaxf(mx, __shfl_xor(mx, 32));
    float sum = 0.f;
    #pragma unroll
    for (int j = 0; j < 16; ++j) { sv[j] = __expf(sv[j] - mx); sum += sv[j]; }
    sum += __shfl_xor(sum, 16);
    sum += __shfl_xor(sum, 32);
    float rinv = 1.0f / sum;
    #pragma unroll
    for (int nt = 0; nt < 4; ++nt) {
      union { unsigned int u[2]; bf16x4 v; } pk;
      pk.u[0] = pk2(sv[nt * 4 + 0] * rinv, sv[nt * 4 + 1] * rinv);
      pk.u[1] = pk2(sv[nt * 4 + 2] * rinv, sv[nt * 4 + 3] * rinv);
      pp[mt][nt] = pk.v;
    }
  }

  // ---- O^T = V^T P^T via K=16 MFMAs; V frags 8B from LDS, P from registers ----
  bf16x4 vf4[4][2];             // [nt(k-token tile)][dt(dim tile)]
  #pragma unroll
  for (int nt = 0; nt < 4; ++nt)
    #pragma unroll
    for (int dt = 0; dt < 2; ++dt) {
      int r = dt * 16 + m15;
      union { uint2 u; bf16x4 v; } ld;
      ld.u = *(const uint2*)(vpb + r * 128 + (((nt * 2 + (quad >> 1)) ^ (r & 7)) << 4) + (quad & 1) * 8);
      vf4[nt][dt] = ld.v;
    }
  f32x4 oacc[4][2];
  #pragma unroll
  for (int tt = 0; tt < 4; ++tt)
    #pragma unroll
    for (int dt = 0; dt < 2; ++dt) {
      f32x4 acc = fz;
      #pragma unroll
      for (int nt = 0; nt < 4; ++nt)
        acc = mfma16(vf4[nt][dt], pp[tt][nt], acc);
      oacc[tt][dt] = acc;
    }
  // O store (overlays V, all reads done): [64 tok][64B], swz ^((row>>1)&3)
  #pragma unroll
  for (int tt = 0; tt < 4; ++tt)
    #pragma unroll
    for (int dt = 0; dt < 2; ++dt) {
      int row = tt * 16 + m15;
      uint2 o;
      o.x = pk2(oacc[tt][dt][0], oacc[tt][dt][1]);
      o.y = pk2(oacc[tt][dt][2], oacc[tt][dt][3]);
      int chunk = dt * 2 + (quad >> 1);
      *(uint2*)(vpb + row * 64 + ((chunk ^ ((row >> 1) & 3)) << 4) + (quad & 1) * 8) = o;
    }
  __syncthreads();

  // ---- proj: swapped mfma(W, O) -> 8B global stores ----
  bf16x8 of[4][4];
  #pragma unroll
  for (int mt = 0; mt < 4; ++mt) {
    int row = mt * 16 + m15;
    int sw = ((row >> 1) & 3) << 4;
    #pragma unroll
    for (int kt = 0; kt < 4; ++kt)
      of[mt][kt] = *(const bf16x8*)(smem + 16384 + kt * 4096 + row * 64 + ((quad << 4) ^ sw));
  }
  int pixo[4];
  #pragma unroll
  for (int mt = 0; mt < 4; ++mt) {
    int token = mt * 16 + m15;
    int ii = token / 7, jj = token - ii * 7;
    int gh = wh * 7 + ii + 3; if (gh >= 112) gh -= 112;   // reverse roll
    int gw = ww * 7 + jj + 3; if (gw >= 112) gw -= 112;
    pixo[mt] = gh * 112 + gw;
  }
  const size_t obase = (size_t)b * 1605632;
  #pragma unroll
  for (int sp = 0; sp < 2; ++sp) {
    int ct = 2 * h + sp;
    bf16x8 wf[4];
    #pragma unroll
    for (int kt = 0; kt < 4; ++kt)
      wf[kt] = *(const bf16x8*)(projw + (ct * 16 + m15) * 128 + kt * 32 + quad * 8);
    float4 pb4 = *(const float4*)(projb + ct * 16 + quad * 4);
    #pragma unroll
    for (int mt = 0; mt < 4; ++mt) {
      f32x4 acc = fz;
      #pragma unroll
      for (int kt = 0; kt < 4; ++kt)
        acc = __builtin_amdgcn_mfma_f32_16x16x32_bf16(wf[kt], of[mt][kt], acc, 0, 0, 0);
      int token = mt * 16 + m15;
      if (token < 49) {
        union { unsigned short u[4]; uint2 v2; } o;
        o.u[0] = f2bf(acc[0] + pb4.x); o.u[1] = f2bf(acc[1] + pb4.y);
        o.u[2] = f2bf(acc[2] + pb4.z); o.u[3] = f2bf(acc[3] + pb4.w);
        *(uint2*)(yw + obase + (size_t)pixo[mt] * 128 + ct * 16 + quad * 4) = o.v2;
      }
    }
  }
}

// ---------------------------------------------------------------------------
// Kernel 3: yws (B,H,W,C) bf16 + shortcut x (B,C,H,W) fp32 -> out fp32 NCHW
// LDS layout [16 c-chunks][112 w][8 ch] (chunk-row stride 1808B):
//   stores are uint4 (conflict-free), reads scalar (conflict-free)
// ---------------------------------------------------------------------------
__global__ __launch_bounds__(256) void k_out(const unsigned short* __restrict__ yws,
                                             const float* __restrict__ x,
                                             float* __restrict__ out) {
  __shared__ __attribute__((aligned(16))) char T[28928];
  int tid = threadIdx.x;
  int bid = blockIdx.x;
  int b = bid / 112;
  int hh = bid - b * 112;
  const unsigned short* src = yws + (size_t)(b * 112 + hh) * 14336;
  #pragma unroll
  for (int it = 0; it < 7; ++it) {
    int cc = tid + it * 256;                 // 1792 chunks of 8 channels
    int w = cc >> 4, ci = cc & 15;
    *(uint4*)(T + ci * 1808 + w * 16) = *(const uint4*)(src + w * 128 + ci * 8);
  }
  __syncthreads();
  int c = tid >> 1, half = tid & 1;
  const char* tr = T + (c >> 3) * 1808 + (c & 7) * 2;
  size_t rowoff = ((size_t)(b * 128 + c) * 112 + hh) * 112;
  const float* xr = x + rowoff;
  float* outr = out + rowoff;
  #pragma unroll
  for (int s2 = 0; s2 < 7; ++s2) {
    int w = half * 56 + s2 * 8;
    float4 xa = *(const float4*)(xr + w);
    float4 xb = *(const float4*)(xr + w + 4);
    float4 oa, ob;
    oa.x = bf2f(*(const unsigned short*)(tr + (w + 0) * 16)) + xa.x;
    oa.y = bf2f(*(const unsigned short*)(tr + (w + 1) * 16)) + xa.y;
    oa.z = bf2f(*(const unsigned short*)(tr + (w + 2) * 16)) + xa.z;
    oa.w = bf2f(*(const unsigned short*)(tr + (w + 3) * 16)) + xa.w;
    ob.x = bf2f(*(const unsigned short*)(tr + (w + 4) * 16)) + xb.x;
    ob.y = bf2f(*(const unsigned short*)(tr + (w + 5) * 16)) + xb.y;
    ob.z = bf2f(*(const unsigned short*)(tr + (w + 6) * 16)) + xb.z;
    ob.w = bf2f(*(const unsigned short*)(tr + (w + 7) * 16)) + xb.w;
    *(float4*)(outr + w) = oa;
    *(float4*)(outr + w + 4) = ob;
  }
}

// ---------------------------------------------------------------------------
extern "C" void kernel_launch(void* const* d_in, const int* in_sizes, int n_in,
                              void* d_out, int out_size, void* d_ws, size_t ws_size,
                              hipStream_t stream) {
  const float* x     = (const float*)d_in[0];
  const float* nw    = (const float*)d_in[1];
  const float* nb    = (const float*)d_in[2];
  const float* qkvw  = (const float*)d_in[3];
  const float* qkvb  = (const float*)d_in[4];
  const float* projw = (const float*)d_in[5];
  const float* projb = (const float*)d_in[6];
  const float* bt    = (const float*)d_in[7];
  const int*   ri    = (const int*)d_in[8];
  const float* am    = (const float*)d_in[9];

  unsigned short* xw   = (unsigned short*)d_ws;                        // 102,760,448 B
  unsigned short* yws  = (unsigned short*)((char*)d_ws + 102760448);   // 102,760,448 B
  float*          bp   = (float*)((char*)d_ws + 205520896);            //      65,536 B
  float*          mp   = (float*)((char*)d_ws + 205586432);            //   4,194,304 B
  unsigned short* qwbf = (unsigned short*)((char*)d_ws + 209780736);   //      98,304 B
  unsigned short* pwbf = (unsigned short*)((char*)d_ws + 209879040);   //      32,768 B
  float* out = (float*)d_out;

  k_prep<<<64,   256, 0, stream>>>(qkvw, projw, qwbf, pwbf);
  k_bias<<<64,   256, 0, stream>>>(bt, ri, bp);
  k_mask<<<4096, 256, 0, stream>>>(am, mp);
  k_ln  <<<1568, 256, 0, stream>>>(x, nw, nb, xw);
  k_attn<<<8192, 256, 0, stream>>>(xw, qwbf, qkvb, pwbf, projb, bp, mp, yws);
  k_out <<<3584, 256, 0, stream>>>(yws, x, out);
}